// Round 6
// baseline (953.677 us; speedup 1.0000x reference)
//
#include <hip/hip_runtime.h>

// Phi3 quantized MLP on MI355X (gfx950) — R6: 8-wave blocks, wave-split outputs.
// R5 post-mortem (per-SIMD accounting): matrix 32%, VALU 11%, LDS 32% busy —
// latency-bound at 2 waves/SIMD (128-reg dual accumulators). Split gate/up
// across waves (512-thr blocks, 64 accum/wave) -> 4 waves/SIMD, 2x TLP.
// Gate->up exchange via LDS in the epilogue (2 passes over staging buffers).

typedef float f32x4 __attribute__((ext_vector_type(4)));
typedef float f32x2 __attribute__((ext_vector_type(2)));
typedef int   i32x4 __attribute__((ext_vector_type(4)));

__device__ __forceinline__ void gload16(const void* g, void* l) {
  __builtin_amdgcn_global_load_lds(
      (const __attribute__((address_space(1))) void*)g,
      (__attribute__((address_space(3))) void*)l, 16, 0, 0);
}

// ---------------- quantize x: f32 -> int8, scale per (row-quad of 4, group of 128) ----------------
__global__ __launch_bounds__(256) void quant_x(const float* __restrict__ x,
                                               signed char* __restrict__ Xq,
                                               float* __restrict__ Xs4) {
  int g    = blockIdx.x;
  int rq   = blockIdx.y;
  int w    = threadIdx.x >> 6;
  int lane = threadIdx.x & 63;
  int row  = rq * 4 + w;
  __shared__ float wmax[4];
  const float2 v = *(const float2*)(x + (size_t)row * 3072 + g * 128 + lane * 2);
  float m = fmaxf(fabsf(v.x), fabsf(v.y));
#pragma unroll
  for (int s = 1; s < 64; s <<= 1) m = fmaxf(m, __shfl_xor(m, s));
  if (lane == 0) wmax[w] = m;
  __syncthreads();
  float m4 = fmaxf(fmaxf(wmax[0], wmax[1]), fmaxf(wmax[2], wmax[3]));
  float inv = m4 > 0.f ? 127.f / m4 : 0.f;
  int qa = (int)rintf(v.x * inv);
  int qb = (int)rintf(v.y * inv);
  unsigned short pk = (unsigned short)((qa & 0xff) | ((qb & 0xff) << 8));
  *(unsigned short*)(Xq + (size_t)row * 3072 + g * 128 + lane * 2) = pk;
  if (threadIdx.x == 0) Xs4[g * 1024 + rq] = m4 * (1.f / 127.f);
}

// ---------------- requant weights: int32 q,z -> int8 (q - z), exact ----------------
template <int K>
__global__ __launch_bounds__(256) void requant_k(const int* __restrict__ qw,
                                                 const int* __restrict__ qz,
                                                 signed char* __restrict__ W) {
  constexpr int KG = K / 128;
  constexpr int perrow = K / 8;
  int idx = blockIdx.x * 256 + threadIdx.x;
  int row = idx / perrow;
  int c8  = idx - row * perrow;
  int k   = c8 << 3;
  int z   = qz[row * KG + (k >> 7)];
  const int4* q4 = (const int4*)(qw + (size_t)row * K + k);
  int4 qa = q4[0];
  int4 qb = q4[1];
  int b0 = ((qa.x - z) & 0xff) | (((qa.y - z) & 0xff) << 8) |
           (((qa.z - z) & 0xff) << 16) | (((qa.w - z) & 0xff) << 24);
  int b1 = ((qb.x - z) & 0xff) | (((qb.y - z) & 0xff) << 8) |
           (((qb.z - z) & 0xff) << 16) | (((qb.w - z) & 0xff) << 24);
  int2 o; o.x = b0; o.y = b1;
  *(int2*)(W + (size_t)row * K + k) = o;
}

// ---------------- scale transpose: [R][G] -> [G][R] ----------------
__global__ __launch_bounds__(256) void transpose_sc(const float* __restrict__ in,
                                                    float* __restrict__ out,
                                                    int R, int G) {
  int idx = blockIdx.x * 256 + threadIdx.x;
  int r = idx / G;
  int g = idx - r * G;
  out[(size_t)g * R + r] = in[idx];
}

// LDS tile: 128 rows x 128 bytes, XOR-swizzled (phys chunk p holds logical p^(row&7)).

// ---------------- GEMM1: act = silu(x@Wg^T)*(x@Wu^T), int8 in, int8 out ----------------
// 512 threads: waves 0-3 gate, 4-7 up; wave w&3 -> 64x64 quadrant.
__global__ __launch_bounds__(512, 4) void gemm_gateup_i8(
    const signed char* __restrict__ Xq, const signed char* __restrict__ Wq,
    const float* __restrict__ Xs4,   // [24][1024]
    const float* __restrict__ GsT,   // [24][16384]
    signed char* __restrict__ act,   // [4096][8192]
    float* __restrict__ As4) {       // [64][1024]
  const int K = 3072;
  const int bid = blockIdx.x;
  const int xcd = bid & 7;
  const int jb  = bid >> 3;
  const int n0  = ((xcd << 3) + (jb & 7)) * 128;
  const int m0  = (jb >> 3) * 128;
  __shared__ signed char lA[16384];
  __shared__ signed char lG[16384];
  __shared__ signed char lU[16384];
  __shared__ float rmaxp[2][64];

  const int tid  = threadIdx.x;
  const int l    = tid & 63;
  const int quad = l >> 4;
  const int l16  = l & 15;
  const int wave = tid >> 6;
  const int isUp = wave >> 2;
  const int w2   = wave & 3;
  const int wcI  = w2 & 1;
  const int wr   = (w2 >> 1) * 64;
  const int wc   = wcI * 64;

  f32x2 f[4][4][2] = {};

  // staging: 1024 chunks/tile, 2 per thread
  int off[2];
#pragma unroll
  for (int jj = 0; jj < 2; ++jj) {
    int c   = tid + 512 * jj;
    int row = c >> 3;
    int log = (c & 7) ^ (row & 7);
    off[jj] = row * K + log * 16;
  }
  const signed char* baseA = Xq + (size_t)m0 * K;
  const signed char* baseG = Wq + (size_t)n0 * K;
  const signed char* baseU = Wq + (size_t)(8192 + n0) * K;
  const signed char* lB    = isUp ? lU : lG;
  const float* sWbase      = GsT + isUp * 8192 + n0 + wc;

  int aoff[2][4], boff[2][4];
#pragma unroll
  for (int h = 0; h < 2; ++h) {
    int slot = h * 4 + quad;
#pragma unroll
    for (int i = 0; i < 4; ++i) {
      int ra = wr + i * 16 + l16;
      aoff[h][i] = ra * 128 + ((slot ^ (ra & 7)) * 16);
      int rb = wc + i * 16 + l16;
      boff[h][i] = rb * 128 + ((slot ^ (rb & 7)) * 16);
    }
  }
  const int qbase = (m0 >> 2) + (wr >> 2) + quad;

  for (int g = 0; g < 24; ++g) {
    const int kk = g << 7;
#pragma unroll
    for (int jj = 0; jj < 2; ++jj) {
      gload16(baseA + off[jj] + kk, lA + (tid + 512 * jj) * 16);
      gload16(baseG + off[jj] + kk, lG + (tid + 512 * jj) * 16);
      gload16(baseU + off[jj] + kk, lU + (tid + 512 * jj) * 16);
    }
    float sxq[4], sw[4];
#pragma unroll
    for (int i = 0; i < 4; ++i) sxq[i] = Xs4[g * 1024 + qbase + i * 4];
#pragma unroll
    for (int jj = 0; jj < 4; ++jj) sw[jj] = sWbase[g * 16384 + jj * 16 + l16];
    __syncthreads();

    i32x4 a[4][2];
#pragma unroll
    for (int i = 0; i < 4; ++i) {
      a[i][0] = *(const i32x4*)(lA + aoff[0][i]);
      a[i][1] = *(const i32x4*)(lA + aoff[1][i]);
    }
#pragma unroll
    for (int jj = 0; jj < 4; ++jj) {
      i32x4 b0 = *(const i32x4*)(lB + boff[0][jj]);
      i32x4 b1 = *(const i32x4*)(lB + boff[1][jj]);
#pragma unroll
      for (int i = 0; i < 4; ++i) {
        i32x4 zero = {0, 0, 0, 0};
        i32x4 ic = __builtin_amdgcn_mfma_i32_16x16x64_i8(a[i][0], b0, zero, 0, 0, 0);
        ic = __builtin_amdgcn_mfma_i32_16x16x64_i8(a[i][1], b1, ic, 0, 0, 0);
        float ps = sxq[i] * sw[jj];
        f32x2 p2 = {ps, ps};
        f32x2 c01 = {(float)ic[0], (float)ic[1]};
        f32x2 c23 = {(float)ic[2], (float)ic[3]};
        f[i][jj][0] = __builtin_elementwise_fma(c01, p2, f[i][jj][0]);
        f[i][jj][1] = __builtin_elementwise_fma(c23, p2, f[i][jj][1]);
      }
    }
    __syncthreads();
  }

  // ---- epilogue: 2 passes; gate waves publish f32 to LDS, up waves finish ----
  float* gb = (float*)(wcI ? lU : lG);   // 64x64 f32 = 16 KB per col-half
#pragma unroll
  for (int p = 0; p < 2; ++p) {
    if (!isUp && (w2 >> 1) == p) {
#pragma unroll
      for (int i = 0; i < 4; ++i)
#pragma unroll
        for (int jj = 0; jj < 4; ++jj)
#pragma unroll
          for (int r = 0; r < 4; ++r)
            gb[(i * 16 + quad * 4 + r) * 64 + jj * 16 + l16] = f[i][jj][r >> 1][r & 1];
    }
    __syncthreads();
    if (isUp && (w2 >> 1) == p) {
      float av[4][4][4];
#pragma unroll
      for (int i = 0; i < 4; ++i)
#pragma unroll
        for (int jj = 0; jj < 4; ++jj)
#pragma unroll
          for (int r = 0; r < 4; ++r) {
            float gv = gb[(i * 16 + quad * 4 + r) * 64 + jj * 16 + l16];
            float uv = f[i][jj][r >> 1][r & 1];
            av[i][jj][r] = (gv / (1.f + __expf(-gv))) * uv;
          }
#pragma unroll
      for (int i = 0; i < 4; ++i)
#pragma unroll
        for (int r = 0; r < 4; ++r) {
          float m = 0.f;
#pragma unroll
          for (int jj = 0; jj < 4; ++jj) m = fmaxf(m, fabsf(av[i][jj][r]));
          m = fmaxf(m, __shfl_xor(m, 1));
          m = fmaxf(m, __shfl_xor(m, 2));
          m = fmaxf(m, __shfl_xor(m, 4));
          m = fmaxf(m, __shfl_xor(m, 8));
          if (l16 == 0) rmaxp[wcI][i * 16 + quad * 4 + r] = m;
        }
      __syncthreads();
#pragma unroll
      for (int i = 0; i < 4; ++i) {
        int lr0 = i * 16 + quad * 4;
        float m4 = 0.f;
#pragma unroll
        for (int r = 0; r < 4; ++r)
          m4 = fmaxf(m4, fmaxf(rmaxp[0][lr0 + r], rmaxp[1][lr0 + r]));
        float inv = m4 > 0.f ? 127.f / m4 : 0.f;
#pragma unroll
        for (int r = 0; r < 4; ++r)
#pragma unroll
          for (int jj = 0; jj < 4; ++jj) {
            int q = (int)rintf(av[i][jj][r] * inv);
            lA[(p * 64 + lr0 + r) * 128 + wc + jj * 16 + l16] = (signed char)q;
          }
        if (l16 == 0 && wcI == 0)
          As4[(n0 >> 7) * 1024 + ((m0 + p * 64 + lr0) >> 2)] = m4 * (1.f / 127.f);
      }
    } else {
      __syncthreads();
    }
    __syncthreads();
  }

#pragma unroll
  for (int t = 0; t < 2; ++t) {
    int c = tid + 512 * t;
    int row = c >> 3;
    int col = (c & 7) * 16;
    *(int4*)(act + (size_t)(m0 + row) * 8192 + n0 + col) = *(const int4*)(lA + row * 128 + col);
  }
}

// ---------------- GEMM2: out = dequant(act)@Wd^T + bias ----------------
// 512 threads, 8 waves x (64x32) tiles.
__global__ __launch_bounds__(512, 4) void gemm_down_i8(
    const signed char* __restrict__ Aq, const signed char* __restrict__ Wq,
    const float* __restrict__ As4,   // [64][1024]
    const float* __restrict__ DsT,   // [64][3072]
    const float* __restrict__ bias,
    float* __restrict__ out) {
  const int K = 8192;
  const int bid = blockIdx.x;
  const int xcd = bid & 7;
  const int jb  = bid >> 3;
  const int jn  = jb % 12;
  const int jm  = jb / 12;
  const int n0  = (12 * (xcd & 1) + jn) * 128;
  const int m0  = (8 * (xcd >> 1) + jm) * 128;
  __shared__ signed char lA[16384];
  __shared__ signed char lB[16384];

  const int tid  = threadIdx.x;
  const int l    = tid & 63;
  const int quad = l >> 4;
  const int l16  = l & 15;
  const int wave = tid >> 6;
  const int wr   = (wave >> 2) * 64;
  const int wc   = (wave & 3) * 32;

  f32x2 fc[4][2][2] = {};

  int off[2];
#pragma unroll
  for (int jj = 0; jj < 2; ++jj) {
    int c   = tid + 512 * jj;
    int row = c >> 3;
    int log = (c & 7) ^ (row & 7);
    off[jj] = row * K + log * 16;
  }
  const signed char* baseA = Aq + (size_t)m0 * K;
  const signed char* baseB = Wq + (size_t)n0 * K;

  int aoff[2][4], boff[2][2];
#pragma unroll
  for (int h = 0; h < 2; ++h) {
    int slot = h * 4 + quad;
#pragma unroll
    for (int i = 0; i < 4; ++i) {
      int ra = wr + i * 16 + l16;
      aoff[h][i] = ra * 128 + ((slot ^ (ra & 7)) * 16);
    }
#pragma unroll
    for (int jj = 0; jj < 2; ++jj) {
      int rb = wc + jj * 16 + l16;
      boff[h][jj] = rb * 128 + ((slot ^ (rb & 7)) * 16);
    }
  }
  const int qbase = (m0 >> 2) + (wr >> 2) + quad;

  for (int g = 0; g < 64; ++g) {
    const int kk = g << 7;
#pragma unroll
    for (int jj = 0; jj < 2; ++jj) {
      gload16(baseA + off[jj] + kk, lA + (tid + 512 * jj) * 16);
      gload16(baseB + off[jj] + kk, lB + (tid + 512 * jj) * 16);
    }
    float sxq[4], sn[2];
#pragma unroll
    for (int i = 0; i < 4; ++i) sxq[i] = As4[g * 1024 + qbase + i * 4];
#pragma unroll
    for (int jj = 0; jj < 2; ++jj)
      sn[jj] = DsT[g * 3072 + n0 + wc + jj * 16 + l16];
    __syncthreads();

    i32x4 a[4][2];
#pragma unroll
    for (int i = 0; i < 4; ++i) {
      a[i][0] = *(const i32x4*)(lA + aoff[0][i]);
      a[i][1] = *(const i32x4*)(lA + aoff[1][i]);
    }
#pragma unroll
    for (int jj = 0; jj < 2; ++jj) {
      i32x4 b0 = *(const i32x4*)(lB + boff[0][jj]);
      i32x4 b1 = *(const i32x4*)(lB + boff[1][jj]);
#pragma unroll
      for (int i = 0; i < 4; ++i) {
        i32x4 zero = {0, 0, 0, 0};
        i32x4 ic = __builtin_amdgcn_mfma_i32_16x16x64_i8(a[i][0], b0, zero, 0, 0, 0);
        ic = __builtin_amdgcn_mfma_i32_16x16x64_i8(a[i][1], b1, ic, 0, 0, 0);
        float ps = sxq[i] * sn[jj];
        f32x2 p2 = {ps, ps};
        f32x2 c01 = {(float)ic[0], (float)ic[1]};
        f32x2 c23 = {(float)ic[2], (float)ic[3]};
        fc[i][jj][0] = __builtin_elementwise_fma(c01, p2, fc[i][jj][0]);
        fc[i][jj][1] = __builtin_elementwise_fma(c23, p2, fc[i][jj][1]);
      }
    }
    __syncthreads();
  }

  float bj[2];
#pragma unroll
  for (int jj = 0; jj < 2; ++jj) bj[jj] = bias[n0 + wc + jj * 16 + l16];

#pragma unroll
  for (int i = 0; i < 4; ++i)
#pragma unroll
    for (int jj = 0; jj < 2; ++jj)
#pragma unroll
      for (int r = 0; r < 4; ++r) {
        int m = m0 + wr + i * 16 + quad * 4 + r;
        int n = n0 + wc + jj * 16 + l16;
        out[(size_t)m * 3072 + n] = fc[i][jj][r >> 1][r & 1] + bj[jj];
      }
}

extern "C" void kernel_launch(void* const* d_in, const int* in_sizes, int n_in,
                              void* d_out, int out_size, void* d_ws, size_t ws_size,
                              hipStream_t stream) {
  const float* x        = (const float*)d_in[0];
  const int*   gup_qw   = (const int*)d_in[1];
  const int*   gup_qz   = (const int*)d_in[2];
  const float* gup_sc   = (const float*)d_in[3];
  const int*   down_qw  = (const int*)d_in[4];
  const int*   down_qz  = (const int*)d_in[5];
  const float* down_sc  = (const float*)d_in[6];
  const float* down_b   = (const float*)d_in[7];
  float* out = (float*)d_out;

  char* ws = (char*)d_ws;
  signed char* Xq    = (signed char*)(ws);                 // 12,582,912
  signed char* Wgupq = (signed char*)(ws + 12582912);      // 50,331,648
  signed char* Wdnq  = (signed char*)(ws + 62914560);      // 25,165,824
  signed char* Actq  = (signed char*)(ws + 88080384);      // 33,554,432
  float* Xs4 = (float*)(ws + 121634816);                   // 24x1024
  float* GsT = (float*)(ws + 121733120);                   // 24x16384
  float* DsT = (float*)(ws + 123305984);                   // 64x3072
  float* As4 = (float*)(ws + 124092416);                   // 64x1024

  quant_x<<<dim3(24, 1024), 256, 0, stream>>>(x, Xq, Xs4);
  requant_k<3072><<<24576, 256, 0, stream>>>(gup_qw, gup_qz, Wgupq);
  requant_k<8192><<<12288, 256, 0, stream>>>(down_qw, down_qz, Wdnq);
  transpose_sc<<<1536, 256, 0, stream>>>(gup_sc, GsT, 16384, 24);
  transpose_sc<<<768, 256, 0, stream>>>(down_sc, DsT, 3072, 64);
  gemm_gateup_i8<<<2048, 512, 0, stream>>>(Xq, Wgupq, Xs4, GsT, Actq, As4);
  gemm_down_i8<<<768, 512, 0, stream>>>(Actq, Wdnq, As4, DsT, down_b, out);
}